// Round 1
// baseline (494.455 us; speedup 1.0000x reference)
//
#include <hip/hip_runtime.h>
#include <stdint.h>

typedef __attribute__((ext_vector_type(8))) short short8;
typedef __attribute__((ext_vector_type(4))) float f32x4;

#define DEVINL __device__ __forceinline__

DEVINL unsigned short f2bf(float f) {
  unsigned u = __float_as_uint(f);
  u = (u + 0x7FFFu + ((u >> 16) & 1u)) >> 16;
  return (unsigned short)u;
}

DEVINL void gload_lds16(const void* g, void* lds) {
  __builtin_amdgcn_global_load_lds(
      (const __attribute__((address_space(1))) unsigned int*)g,
      (__attribute__((address_space(3))) unsigned int*)lds, 16, 0, 0);
}

// ---------------- conversion kernels ----------------

__global__ void cvt4(const float* __restrict__ in, unsigned short* __restrict__ out,
                     float scale, int n4) {
  int i = blockIdx.x * blockDim.x + threadIdx.x;
  if (i >= n4) return;
  float4 v = ((const float4*)in)[i];
  ushort4 o;
  o.x = f2bf(v.x * scale); o.y = f2bf(v.y * scale);
  o.z = f2bf(v.z * scale); o.w = f2bf(v.w * scale);
  ((ushort4*)out)[i] = o;
}

// out[Nd][Kd] = in[Kd][Nd]  (bf16 convert)
__global__ void transpose_cvt(const float* __restrict__ in, unsigned short* __restrict__ out,
                              int Kd, int Nd) {
  int k = blockIdx.x * 32 + (threadIdx.x & 31);
  int n = blockIdx.y * 8 + (threadIdx.x >> 5);
  if (k < Kd && n < Nd) out[(size_t)n * Kd + k] = f2bf(in[(size_t)k * Nd + n]);
}

// WoT[d][h*64+e] = Wo[h][d][e] ; Wo is [8][512][64]
__global__ void wo_repack(const float* __restrict__ in, unsigned short* __restrict__ out) {
  int idx = blockIdx.x * 256 + threadIdx.x;
  if (idx >= 512 * 512) return;
  int d = idx >> 9, j = idx & 511, h = j >> 6, e = j & 63;
  out[idx] = f2bf(in[(size_t)h * 32768 + (size_t)d * 64 + e]);
}

// ---------------- GEMM: C[M,N] = A[M,K] * Bt[N,K]^T (+bias)(+relu) ----------------
// EPI: 0 = none, 1 = +bias, 2 = +bias+relu.  TOut: unsigned short (bf16) or float.
template <int EPI, typename TOut>
__global__ __launch_bounds__(256) void gemm_bt(
    const unsigned short* __restrict__ A, const unsigned short* __restrict__ Bt,
    const float* __restrict__ bias, TOut* __restrict__ C, int M, int N, int K) {
  __shared__ __align__(16) unsigned short As[128 * 32];
  __shared__ __align__(16) unsigned short Bs[128 * 32];
  const int m0 = blockIdx.x * 128, n0 = blockIdx.y * 128;
  const int tid = threadIdx.x, w = tid >> 6, l = tid & 63;
  const int wm = w >> 1, wn = w & 1;
  const int lr = l & 15, lg = l >> 4;

  f32x4 zero4 = {0.f, 0.f, 0.f, 0.f};
  f32x4 acc[4][4];
#pragma unroll
  for (int i = 0; i < 4; ++i)
#pragma unroll
    for (int j = 0; j < 4; ++j) acc[i][j] = zero4;

  for (int k0 = 0; k0 < K; k0 += 32) {
#pragma unroll
    for (int i = 0; i < 2; ++i) {
      const int cb = w * 64 + i * 256;      // wave-uniform chunk base
      const int c = cb + l;                 // 16B chunk id, 0..511
      const int row = c >> 2, ce = (c & 3) * 8;
      gload_lds16(A + (size_t)(m0 + row) * K + k0 + ce, (char*)As + cb * 16);
      gload_lds16(Bt + (size_t)(n0 + row) * K + k0 + ce, (char*)Bs + cb * 16);
    }
    asm volatile("s_waitcnt vmcnt(0)" ::: "memory");
    __syncthreads();

    short8 af[4], bf[4];
#pragma unroll
    for (int mi = 0; mi < 4; ++mi)
      af[mi] = *(const short8*)&As[(wm * 64 + mi * 16 + lr) * 32 + lg * 8];
#pragma unroll
    for (int ni = 0; ni < 4; ++ni)
      bf[ni] = *(const short8*)&Bs[(wn * 64 + ni * 16 + lr) * 32 + lg * 8];
#pragma unroll
    for (int mi = 0; mi < 4; ++mi)
#pragma unroll
      for (int ni = 0; ni < 4; ++ni)
        acc[mi][ni] = __builtin_amdgcn_mfma_f32_16x16x32_bf16(af[mi], bf[ni], acc[mi][ni], 0, 0, 0);
    __syncthreads();
  }

#pragma unroll
  for (int ni = 0; ni < 4; ++ni) {
    const int col = n0 + wn * 64 + ni * 16 + lr;
    float bv = (EPI >= 1) ? bias[col] : 0.f;
#pragma unroll
    for (int mi = 0; mi < 4; ++mi) {
      const int row = m0 + wm * 64 + mi * 16 + lg * 4;
#pragma unroll
      for (int r = 0; r < 4; ++r) {
        float v = acc[mi][ni][r] + bv;
        if (EPI == 2) v = fmaxf(v, 0.f);
        if constexpr (sizeof(TOut) == 2)
          C[(size_t)(row + r) * N + col] = (TOut)f2bf(v);
        else
          C[(size_t)(row + r) * N + col] = v;
      }
    }
  }
}

// ---------------- flash attention ----------------
// Q,K,V,O: [B*2048, 512] bf16, head h occupies cols h*64..h*64+63.
// grid (64 = b*8+h, 32 q-tiles), block 256 (4 waves x 16 q-rows).
__global__ __launch_bounds__(256) void attn64(
    const unsigned short* __restrict__ Q, const unsigned short* __restrict__ Kh,
    const unsigned short* __restrict__ V, unsigned short* __restrict__ O) {
  const int bh = blockIdx.x, b = bh >> 3, h = bh & 7;
  const int q0 = blockIdx.y * 64;
  const int tid = threadIdx.x, w = tid >> 6, l = tid & 63;
  const int lr = l & 15, lg = l >> 4;
  const size_t baseBH = (size_t)b * 2048 * 512 + (size_t)h * 64;

  __shared__ __align__(16) unsigned short Kl[64 * 64];      // row-major, 16B-chunk XOR swizzled
  __shared__ __align__(16) unsigned short Vt[64 * 72];      // V^T: [e][k], padded
  __shared__ __align__(16) unsigned short Pl[4][16 * 72];   // per-wave P, padded

  // Q fragments (A operand, rows = q0 + w*16 + lr, k-dim = head dim 64)
  short8 qf[2];
  {
    const unsigned short* qp = Q + baseBH + (size_t)(q0 + w * 16 + lr) * 512 + lg * 8;
    qf[0] = *(const short8*)qp;
    qf[1] = *(const short8*)(qp + 32);
  }

  f32x4 zero4 = {0.f, 0.f, 0.f, 0.f};
  float m_run[4], l_run[4];
  f32x4 oa[4];
#pragma unroll
  for (int r = 0; r < 4; ++r) { m_run[r] = -1e30f; l_run[r] = 0.f; }
#pragma unroll
  for (int et = 0; et < 4; ++et) oa[et] = zero4;

  for (int k0 = 0; k0 < 2048; k0 += 64) {
    // ---- stage K (swizzled) and V^T ----
#pragma unroll
    for (int i = 0; i < 2; ++i) {
      int c = tid + i * 256;              // 0..511 : 16B chunks of a 64x64 bf16 tile
      int row = c >> 3, cr = c & 7;
      const unsigned short* gk = Kh + baseBH + (size_t)(k0 + row) * 512 + cr * 8;
      short8 kv = *(const short8*)gk;
      *(short8*)((char*)Kl + row * 128 + ((cr ^ (row & 7)) * 16)) = kv;
      const unsigned short* gv = V + baseBH + (size_t)(k0 + row) * 512 + cr * 8;
      short8 vv = *(const short8*)gv;
#pragma unroll
      for (int j = 0; j < 8; ++j)
        Vt[(cr * 8 + j) * 72 + row] = (unsigned short)vv[j];
    }
    __syncthreads();

    // ---- S = Q K^T (scale folded into Wq) ----
    f32x4 s[4];
#pragma unroll
    for (int nt = 0; nt < 4; ++nt) {
      s[nt] = zero4;
#pragma unroll
      for (int kc = 0; kc < 2; ++kc) {
        int row = nt * 16 + lr;
        int cr = lg + kc * 4;
        short8 bfr = *(const short8*)((const char*)Kl + row * 128 + (((cr ^ (row & 7))) * 16));
        s[nt] = __builtin_amdgcn_mfma_f32_16x16x32_bf16(qf[kc], bfr, s[nt], 0, 0, 0);
      }
    }

    // ---- online softmax (f32) ----
    float p[4][4];
#pragma unroll
    for (int r = 0; r < 4; ++r) {
      float mt = fmaxf(fmaxf(s[0][r], s[1][r]), fmaxf(s[2][r], s[3][r]));
#pragma unroll
      for (int off = 1; off < 16; off <<= 1) mt = fmaxf(mt, __shfl_xor(mt, off, 64));
      float mn = fmaxf(m_run[r], mt);
      float alpha = exp2f((m_run[r] - mn) * 1.44269504f);
      m_run[r] = mn;
      float rs = 0.f;
#pragma unroll
      for (int nt = 0; nt < 4; ++nt) {
        float pv = exp2f((s[nt][r] - mn) * 1.44269504f);
        p[nt][r] = pv;
        rs += pv;
      }
#pragma unroll
      for (int off = 1; off < 16; off <<= 1) rs += __shfl_xor(rs, off, 64);
      l_run[r] = l_run[r] * alpha + rs;
#pragma unroll
      for (int et = 0; et < 4; ++et) oa[et][r] *= alpha;
    }

    // ---- P -> LDS (bf16), reshape to A-operand ----
#pragma unroll
    for (int nt = 0; nt < 4; ++nt)
#pragma unroll
      for (int r = 0; r < 4; ++r)
        Pl[w][(4 * lg + r) * 72 + nt * 16 + lr] = f2bf(p[nt][r]);
    asm volatile("s_waitcnt lgkmcnt(0)" ::: "memory");

    // ---- O += P V ----
#pragma unroll
    for (int kc = 0; kc < 2; ++kc) {
      short8 pa = *(const short8*)&Pl[w][lr * 72 + lg * 8 + 32 * kc];
#pragma unroll
      for (int et = 0; et < 4; ++et) {
        short8 bv = *(const short8*)&Vt[(et * 16 + lr) * 72 + lg * 8 + 32 * kc];
        oa[et] = __builtin_amdgcn_mfma_f32_16x16x32_bf16(pa, bv, oa[et], 0, 0, 0);
      }
    }
    __syncthreads();
  }

  // ---- epilogue ----
#pragma unroll
  for (int et = 0; et < 4; ++et)
#pragma unroll
    for (int r = 0; r < 4; ++r) {
      float v = oa[et][r] / l_run[r];
      O[baseBH + (size_t)(q0 + w * 16 + 4 * lg + r) * 512 + et * 16 + lr] = f2bf(v);
    }
}

// ---------------- host launch ----------------

extern "C" void kernel_launch(void* const* d_in, const int* in_sizes, int n_in,
                              void* d_out, int out_size, void* d_ws, size_t ws_size,
                              hipStream_t stream) {
  const float* x1 = (const float*)d_in[0];
  const float* x2 = (const float*)d_in[1];
  const float* r  = (const float*)d_in[2];
  const float* W1 = (const float*)d_in[3];
  const float* b1 = (const float*)d_in[4];
  const float* W2 = (const float*)d_in[5];
  const float* b2 = (const float*)d_in[6];
  const float* Wq = (const float*)d_in[7];
  const float* Wk = (const float*)d_in[8];
  const float* Wv = (const float*)d_in[9];
  const float* Wo = (const float*)d_in[10];

  char* ws = (char*)d_ws;
  size_t off = 0;
  auto alloc = [&](size_t bytes) {
    char* p = ws + off;
    off = (off + bytes + 255) & ~(size_t)255;
    return p;
  };
  unsigned short* W1T = (unsigned short*)alloc(512 * 128 * 2);
  unsigned short* W2T = (unsigned short*)alloc(512 * 512 * 2);
  unsigned short* WqB = (unsigned short*)alloc(512 * 512 * 2);
  unsigned short* WkB = (unsigned short*)alloc(512 * 512 * 2);
  unsigned short* WvB = (unsigned short*)alloc(512 * 512 * 2);
  unsigned short* WoT = (unsigned short*)alloc(512 * 512 * 2);
  unsigned short* Xb  = (unsigned short*)alloc((size_t)16384 * 128 * 2);
  unsigned short* Hb  = (unsigned short*)alloc((size_t)16384 * 512 * 2);  // also reused as O
  unsigned short* Qb  = (unsigned short*)alloc((size_t)16384 * 512 * 2);
  unsigned short* Kb  = (unsigned short*)alloc((size_t)16384 * 512 * 2);
  unsigned short* Rb  = (unsigned short*)alloc((size_t)16384 * 512 * 2);
  unsigned short* QHb = (unsigned short*)alloc((size_t)16384 * 512 * 2);
  unsigned short* KHb = (unsigned short*)alloc((size_t)16384 * 512 * 2);
  unsigned short* VHb = (unsigned short*)alloc((size_t)16384 * 512 * 2);
  unsigned short* Ob  = Hb;

  const dim3 gBig(128, 4);  // 16384/128 x 512/128

  // weight prep
  transpose_cvt<<<dim3(4, 64), 256, 0, stream>>>(W1, W1T, 128, 512);
  transpose_cvt<<<dim3(16, 64), 256, 0, stream>>>(W2, W2T, 512, 512);
  cvt4<<<256, 256, 0, stream>>>(Wq, WqB, 0.125f, 65536);  // fold 1/sqrt(hd)
  cvt4<<<256, 256, 0, stream>>>(Wk, WkB, 1.0f, 65536);
  cvt4<<<256, 256, 0, stream>>>(Wv, WvB, 1.0f, 65536);
  wo_repack<<<1024, 256, 0, stream>>>(Wo, WoT);

  // k = mlp(x1)
  cvt4<<<2048, 256, 0, stream>>>(x1, Xb, 1.0f, 524288);
  gemm_bt<2, unsigned short><<<gBig, 256, 0, stream>>>(Xb, W1T, b1, Hb, 16384, 512, 128);
  gemm_bt<1, unsigned short><<<gBig, 256, 0, stream>>>(Hb, W2T, b2, Kb, 16384, 512, 512);
  // q = mlp(x2)
  cvt4<<<2048, 256, 0, stream>>>(x2, Xb, 1.0f, 524288);
  gemm_bt<2, unsigned short><<<gBig, 256, 0, stream>>>(Xb, W1T, b1, Hb, 16384, 512, 128);
  gemm_bt<1, unsigned short><<<gBig, 256, 0, stream>>>(Hb, W2T, b2, Qb, 16384, 512, 512);
  // head projections
  cvt4<<<8192, 256, 0, stream>>>(r, Rb, 1.0f, 2097152);
  gemm_bt<0, unsigned short><<<gBig, 256, 0, stream>>>(Qb, WqB, nullptr, QHb, 16384, 512, 512);
  gemm_bt<0, unsigned short><<<gBig, 256, 0, stream>>>(Kb, WkB, nullptr, KHb, 16384, 512, 512);
  gemm_bt<0, unsigned short><<<gBig, 256, 0, stream>>>(Rb, WvB, nullptr, VHb, 16384, 512, 512);
  // attention
  attn64<<<dim3(64, 32), 256, 0, stream>>>(QHb, KHb, VHb, Ob);
  // output projection -> f32
  gemm_bt<0, float><<<gBig, 256, 0, stream>>>(Ob, WoT, nullptr, (float*)d_out, 16384, 512, 512);
}

// Round 2
// 343.944 us; speedup vs baseline: 1.4376x; 1.4376x over previous
//
#include <hip/hip_runtime.h>
#include <stdint.h>

typedef __attribute__((ext_vector_type(8))) short short8;
typedef __attribute__((ext_vector_type(4))) float f32x4;

#define DEVINL __device__ __forceinline__

DEVINL unsigned short f2bf(float f) {
  unsigned u = __float_as_uint(f);
  u = (u + 0x7FFFu + ((u >> 16) & 1u)) >> 16;
  return (unsigned short)u;
}

DEVINL float bf2f(unsigned short s) {
  return __uint_as_float(((unsigned)s) << 16);
}

DEVINL void gload_lds16(const void* g, void* lds) {
  __builtin_amdgcn_global_load_lds(
      (const __attribute__((address_space(1))) unsigned int*)g,
      (__attribute__((address_space(3))) unsigned int*)lds, 16, 0, 0);
}

template <int IMM> DEVINL float swz_f(float x) {
  return __int_as_float(__builtin_amdgcn_ds_swizzle(__float_as_int(x), IMM));
}

// ---------------- conversion kernels ----------------

__global__ void cvt4(const float* __restrict__ in, unsigned short* __restrict__ out,
                     float scale, int n4) {
  int i = blockIdx.x * blockDim.x + threadIdx.x;
  if (i >= n4) return;
  float4 v = ((const float4*)in)[i];
  ushort4 o;
  o.x = f2bf(v.x * scale); o.y = f2bf(v.y * scale);
  o.z = f2bf(v.z * scale); o.w = f2bf(v.w * scale);
  ((ushort4*)out)[i] = o;
}

// out[Nd][Kd] = in[Kd][Nd]  (bf16 convert)
__global__ void transpose_cvt(const float* __restrict__ in, unsigned short* __restrict__ out,
                              int Kd, int Nd) {
  int k = blockIdx.x * 32 + (threadIdx.x & 31);
  int n = blockIdx.y * 8 + (threadIdx.x >> 5);
  if (k < Kd && n < Nd) out[(size_t)n * Kd + k] = f2bf(in[(size_t)k * Nd + n]);
}

// WoT[d][h*64+e] = Wo[h][d][e] ; Wo is [8][512][64]
__global__ void wo_repack(const float* __restrict__ in, unsigned short* __restrict__ out) {
  int idx = blockIdx.x * 256 + threadIdx.x;
  if (idx >= 512 * 512) return;
  int d = idx >> 9, j = idx & 511, h = j >> 6, e = j & 63;
  out[idx] = f2bf(in[(size_t)h * 32768 + (size_t)d * 64 + e]);
}

// out[e] = sum_d b[d] * bf2f(W[e*512+d]) ; grid 512 blocks x 64 threads
__global__ void bias_fold(const float* __restrict__ b, const unsigned short* __restrict__ W,
                          float* __restrict__ out) {
  int e = blockIdx.x, l = threadIdx.x;
  short8 wv = *(const short8*)&W[(size_t)e * 512 + l * 8];
  float acc = 0.f;
#pragma unroll
  for (int j = 0; j < 8; ++j)
    acc += b[l * 8 + j] * bf2f((unsigned short)wv[j]);
#pragma unroll
  for (int off = 1; off < 64; off <<= 1) acc += __shfl_xor(acc, off, 64);
  if (l == 0) out[e] = acc;
}

// VT[((bh)*64 + e)*2048 + n] = VH[(b*2048+n)*512 + h*64 + e]
// grid (64 bh, 16 ntiles) x 256 threads
__global__ __launch_bounds__(256) void v_transpose(const unsigned short* __restrict__ VH,
                                                   unsigned short* __restrict__ VT) {
  const int bh = blockIdx.x, t = blockIdx.y;
  const int b = bh >> 3, h = bh & 7;
  __shared__ __align__(16) unsigned short L[128 * 72];
  const int tid = threadIdx.x;
#pragma unroll
  for (int i = 0; i < 4; ++i) {
    int c = i * 256 + tid, kk = c >> 3, cr = c & 7;
    *(short8*)&L[kk * 72 + cr * 8] =
        *(const short8*)&VH[(size_t)(b * 2048 + t * 128 + kk) * 512 + h * 64 + cr * 8];
  }
  __syncthreads();
#pragma unroll
  for (int i = 0; i < 4; ++i) {
    int c = i * 256 + tid, e = c >> 4, ckn = c & 15;
    short8 v;
#pragma unroll
    for (int j = 0; j < 8; ++j) v[j] = L[(ckn * 8 + j) * 72 + e];
    *(short8*)&VT[((size_t)bh * 64 + e) * 2048 + t * 128 + ckn * 8] = v;
  }
}

// ---------------- GEMM: C[M,N] = A[M,K] * Bt[N,K]^T (+bias)(+relu) ----------------
template <int EPI, typename TOut>
__global__ __launch_bounds__(256) void gemm_bt(
    const unsigned short* __restrict__ A, const unsigned short* __restrict__ Bt,
    const float* __restrict__ bias, TOut* __restrict__ C, int M, int N, int K) {
  __shared__ __align__(16) unsigned short As[128 * 32];
  __shared__ __align__(16) unsigned short Bs[128 * 32];
  const int m0 = blockIdx.x * 128, n0 = blockIdx.y * 128;
  const int tid = threadIdx.x, w = tid >> 6, l = tid & 63;
  const int wm = w >> 1, wn = w & 1;
  const int lr = l & 15, lg = l >> 4;

  f32x4 zero4 = {0.f, 0.f, 0.f, 0.f};
  f32x4 acc[4][4];
#pragma unroll
  for (int i = 0; i < 4; ++i)
#pragma unroll
    for (int j = 0; j < 4; ++j) acc[i][j] = zero4;

  for (int k0 = 0; k0 < K; k0 += 32) {
#pragma unroll
    for (int i = 0; i < 2; ++i) {
      const int cb = w * 64 + i * 256;
      const int c = cb + l;
      const int row = c >> 2, ce = (c & 3) * 8;
      gload_lds16(A + (size_t)(m0 + row) * K + k0 + ce, (char*)As + cb * 16);
      gload_lds16(Bt + (size_t)(n0 + row) * K + k0 + ce, (char*)Bs + cb * 16);
    }
    asm volatile("s_waitcnt vmcnt(0)" ::: "memory");
    __syncthreads();

    short8 af[4], bf[4];
#pragma unroll
    for (int mi = 0; mi < 4; ++mi)
      af[mi] = *(const short8*)&As[(wm * 64 + mi * 16 + lr) * 32 + lg * 8];
#pragma unroll
    for (int ni = 0; ni < 4; ++ni)
      bf[ni] = *(const short8*)&Bs[(wn * 64 + ni * 16 + lr) * 32 + lg * 8];
#pragma unroll
    for (int mi = 0; mi < 4; ++mi)
#pragma unroll
      for (int ni = 0; ni < 4; ++ni)
        acc[mi][ni] = __builtin_amdgcn_mfma_f32_16x16x32_bf16(af[mi], bf[ni], acc[mi][ni], 0, 0, 0);
    __syncthreads();
  }

#pragma unroll
  for (int ni = 0; ni < 4; ++ni) {
    const int col = n0 + wn * 64 + ni * 16 + lr;
    float bv = (EPI >= 1) ? bias[col] : 0.f;
#pragma unroll
    for (int mi = 0; mi < 4; ++mi) {
      const int row = m0 + wm * 64 + mi * 16 + lg * 4;
#pragma unroll
      for (int r = 0; r < 4; ++r) {
        float v = acc[mi][ni][r] + bv;
        if (EPI == 2) v = fmaxf(v, 0.f);
        if constexpr (sizeof(TOut) == 2)
          C[(size_t)(row + r) * N + col] = (TOut)f2bf(v);
        else
          C[(size_t)(row + r) * N + col] = v;
      }
    }
  }
}

// ---------------- flash attention, KBLK=128 ----------------
// Q: [B*2048, 512] bf16 head-sliced; Kh same; VT: [bh][64 e][2048 n] bf16.
// grid (64 = b*8+h, 32 q-tiles), block 256 (4 waves x 16 q-rows).
__global__ __launch_bounds__(256) void attn128(
    const unsigned short* __restrict__ Q, const unsigned short* __restrict__ Kh,
    const unsigned short* __restrict__ VT, unsigned short* __restrict__ O) {
  const int bh = blockIdx.x, b = bh >> 3, h = bh & 7;
  const int q0 = blockIdx.y * 64;
  const int tid = threadIdx.x, w = tid >> 6, l = tid & 63;
  const int lr = l & 15, lg = l >> 4;
  const size_t baseBH = (size_t)b * 2048 * 512 + (size_t)h * 64;
  const size_t baseVT = (size_t)bh * 64 * 2048;

  __shared__ __align__(16) unsigned short Kl[128 * 64];   // [key][d], 16B-chunk XOR swizzled
  __shared__ __align__(16) unsigned short Vt[64 * 128];   // [e][k], 16B-chunk XOR swizzled
  __shared__ __align__(16) unsigned short Pl[4][16 * 136];

  short8 qf[2];
  {
    const unsigned short* qp = Q + baseBH + (size_t)(q0 + w * 16 + lr) * 512 + lg * 8;
    qf[0] = *(const short8*)qp;
    qf[1] = *(const short8*)(qp + 32);
  }

  f32x4 zero4 = {0.f, 0.f, 0.f, 0.f};
  float m_run[4], l_run[4];
  f32x4 oa[4];
#pragma unroll
  for (int r = 0; r < 4; ++r) { m_run[r] = -1e30f; l_run[r] = 0.f; }
#pragma unroll
  for (int et = 0; et < 4; ++et) oa[et] = zero4;

  for (int k0 = 0; k0 < 2048; k0 += 128) {
    // ---- stage K and V^T via global_load_lds, pre-swizzled global source ----
#pragma unroll
    for (int i = 0; i < 4; ++i) {
      const int c = w * 256 + i * 64 + l;          // 16B chunk id, 0..1023
      const int kk = c >> 3, cr = c & 7;           // K tile: [128 keys][8 chunks]
      gload_lds16(Kh + baseBH + (size_t)(k0 + kk) * 512 + ((cr ^ (kk & 7)) * 8),
                  (char*)Kl + (w * 256 + i * 64) * 16);
      const int e = c >> 4, ck = c & 15;           // V tile: [64 e][16 chunks]
      gload_lds16(VT + baseVT + (size_t)e * 2048 + k0 + ((ck ^ (e & 7)) * 8),
                  (char*)Vt + (w * 256 + i * 64) * 16);
    }
    asm volatile("s_waitcnt vmcnt(0)" ::: "memory");
    __syncthreads();

    // ---- S = Q K^T (scale folded into Wq) ----
    f32x4 s[8];
#pragma unroll
    for (int nt = 0; nt < 8; ++nt) {
      s[nt] = zero4;
      const int kk = nt * 16 + lr;
#pragma unroll
      for (int kc = 0; kc < 2; ++kc) {
        const int cr = kc * 4 + lg;
        short8 bfr = *(const short8*)((const char*)Kl + kk * 128 + ((cr ^ (kk & 7)) * 16));
        s[nt] = __builtin_amdgcn_mfma_f32_16x16x32_bf16(qf[kc], bfr, s[nt], 0, 0, 0);
      }
    }

    // ---- online softmax (f32), reduce over 16 lanes via ds_swizzle ----
#pragma unroll
    for (int r = 0; r < 4; ++r) {
      float mt = s[0][r];
#pragma unroll
      for (int nt = 1; nt < 8; ++nt) mt = fmaxf(mt, s[nt][r]);
      mt = fmaxf(mt, swz_f<0x041F>(mt));
      mt = fmaxf(mt, swz_f<0x081F>(mt));
      mt = fmaxf(mt, swz_f<0x101F>(mt));
      mt = fmaxf(mt, swz_f<0x201F>(mt));
      float mn = fmaxf(m_run[r], mt);
      float alpha = exp2f((m_run[r] - mn) * 1.44269504f);
      m_run[r] = mn;
      float rs = 0.f;
#pragma unroll
      for (int nt = 0; nt < 8; ++nt) {
        float pv = exp2f((s[nt][r] - mn) * 1.44269504f);
        s[nt][r] = pv;
        rs += pv;
      }
      rs += swz_f<0x041F>(rs);
      rs += swz_f<0x081F>(rs);
      rs += swz_f<0x101F>(rs);
      rs += swz_f<0x201F>(rs);
      l_run[r] = l_run[r] * alpha + rs;
#pragma unroll
      for (int et = 0; et < 4; ++et) oa[et][r] *= alpha;
    }

    // ---- P -> LDS (bf16), reshape to A-operand ----
#pragma unroll
    for (int nt = 0; nt < 8; ++nt)
#pragma unroll
      for (int r = 0; r < 4; ++r)
        Pl[w][(4 * lg + r) * 136 + nt * 16 + lr] = f2bf(s[nt][r]);
    asm volatile("s_waitcnt lgkmcnt(0)" ::: "memory");
    __builtin_amdgcn_sched_barrier(0);

    // ---- O += P V ----
#pragma unroll
    for (int kcc = 0; kcc < 4; ++kcc) {
      short8 pa = *(const short8*)((const char*)Pl[w] + lr * 272 + kcc * 64 + lg * 16);
#pragma unroll
      for (int et = 0; et < 4; ++et) {
        const int e = et * 16 + lr;
        const int ck = kcc * 4 + lg;
        short8 bv = *(const short8*)((const char*)Vt + e * 256 + ((ck ^ (e & 7)) * 16));
        oa[et] = __builtin_amdgcn_mfma_f32_16x16x32_bf16(pa, bv, oa[et], 0, 0, 0);
      }
    }
    __syncthreads();
  }

  // ---- epilogue ----
#pragma unroll
  for (int et = 0; et < 4; ++et)
#pragma unroll
    for (int r = 0; r < 4; ++r) {
      float v = oa[et][r] / l_run[r];
      O[baseBH + (size_t)(q0 + w * 16 + 4 * lg + r) * 512 + et * 16 + lr] = f2bf(v);
    }
}

// ---------------- host launch ----------------

extern "C" void kernel_launch(void* const* d_in, const int* in_sizes, int n_in,
                              void* d_out, int out_size, void* d_ws, size_t ws_size,
                              hipStream_t stream) {
  const float* x1 = (const float*)d_in[0];
  const float* x2 = (const float*)d_in[1];
  const float* r  = (const float*)d_in[2];
  const float* W1 = (const float*)d_in[3];
  const float* b1 = (const float*)d_in[4];
  const float* W2 = (const float*)d_in[5];
  const float* b2 = (const float*)d_in[6];
  const float* Wq = (const float*)d_in[7];
  const float* Wk = (const float*)d_in[8];
  const float* Wv = (const float*)d_in[9];
  const float* Wo = (const float*)d_in[10];

  char* ws = (char*)d_ws;
  size_t off = 0;
  auto alloc = [&](size_t bytes) {
    char* p = ws + off;
    off = (off + bytes + 255) & ~(size_t)255;
    return p;
  };
  unsigned short* W1T = (unsigned short*)alloc(512 * 128 * 2);
  unsigned short* W2B = (unsigned short*)alloc(512 * 512 * 2);
  unsigned short* WqB = (unsigned short*)alloc(512 * 512 * 2);
  unsigned short* WkB = (unsigned short*)alloc(512 * 512 * 2);
  unsigned short* WvB = (unsigned short*)alloc(512 * 512 * 2);
  unsigned short* WoT = (unsigned short*)alloc(512 * 512 * 2);
  unsigned short* Fq  = (unsigned short*)alloc(512 * 512 * 2);
  unsigned short* Fk  = (unsigned short*)alloc(512 * 512 * 2);
  float* bqf = (float*)alloc(512 * 4);
  float* bkf = (float*)alloc(512 * 4);
  unsigned short* Xb  = (unsigned short*)alloc((size_t)16384 * 128 * 2);
  unsigned short* Hb  = (unsigned short*)alloc((size_t)16384 * 512 * 2);
  unsigned short* Rb  = (unsigned short*)alloc((size_t)16384 * 512 * 2);  // reused as VT
  unsigned short* QHb = (unsigned short*)alloc((size_t)16384 * 512 * 2);  // reused as O
  unsigned short* KHb = (unsigned short*)alloc((size_t)16384 * 512 * 2);
  unsigned short* VHb = (unsigned short*)alloc((size_t)16384 * 512 * 2);
  unsigned short* VT  = Rb;
  unsigned short* Ob  = QHb;

  const dim3 gBig(128, 4);   // 16384/128 x 512/128
  const dim3 gW(4, 4);       // 512/128 x 512/128

  // ---- weight prep ----
  transpose_cvt<<<dim3(4, 64), 256, 0, stream>>>(W1, W1T, 128, 512);
  cvt4<<<256, 256, 0, stream>>>(W2, W2B, 1.0f, 65536);
  cvt4<<<256, 256, 0, stream>>>(Wq, WqB, 0.125f, 65536);   // fold 1/sqrt(hd)
  cvt4<<<256, 256, 0, stream>>>(Wk, WkB, 1.0f, 65536);
  cvt4<<<256, 256, 0, stream>>>(Wv, WvB, 1.0f, 65536);
  wo_repack<<<1024, 256, 0, stream>>>(Wo, WoT);
  // fold W2 into head projections: Fq[e'][c] = sum_d WqB[e'][d] * W2[c][d]
  gemm_bt<0, unsigned short><<<gW, 256, 0, stream>>>(WqB, W2B, nullptr, Fq, 512, 512, 512);
  gemm_bt<0, unsigned short><<<gW, 256, 0, stream>>>(WkB, W2B, nullptr, Fk, 512, 512, 512);
  bias_fold<<<512, 64, 0, stream>>>(b2, WqB, bqf);
  bias_fold<<<512, 64, 0, stream>>>(b2, WkB, bkf);

  // ---- k path: KH = relu(x1 W1 + b1) Fq^T + bq ----
  cvt4<<<2048, 256, 0, stream>>>(x1, Xb, 1.0f, 524288);
  gemm_bt<2, unsigned short><<<gBig, 256, 0, stream>>>(Xb, W1T, b1, Hb, 16384, 512, 128);
  gemm_bt<1, unsigned short><<<gBig, 256, 0, stream>>>(Hb, Fk, bkf, KHb, 16384, 512, 512);
  // ---- q path ----
  cvt4<<<2048, 256, 0, stream>>>(x2, Xb, 1.0f, 524288);
  gemm_bt<2, unsigned short><<<gBig, 256, 0, stream>>>(Xb, W1T, b1, Hb, 16384, 512, 128);
  gemm_bt<1, unsigned short><<<gBig, 256, 0, stream>>>(Hb, Fq, bqf, QHb, 16384, 512, 512);
  // ---- v path ----
  cvt4<<<8192, 256, 0, stream>>>(r, Rb, 1.0f, 2097152);
  gemm_bt<0, unsigned short><<<gBig, 256, 0, stream>>>(Rb, WvB, nullptr, VHb, 16384, 512, 512);
  v_transpose<<<dim3(64, 16), 256, 0, stream>>>(VHb, VT);
  // ---- attention (O aliases QHb: each block writes exactly the rows it read) ----
  attn128<<<dim3(64, 32), 256, 0, stream>>>(QHb, KHb, VT, Ob);
  // ---- output projection -> f32 ----
  gemm_bt<0, float><<<gBig, 256, 0, stream>>>(Ob, WoT, nullptr, (float*)d_out, 16384, 512, 512);
}

// Round 3
// 250.301 us; speedup vs baseline: 1.9754x; 1.3741x over previous
//
#include <hip/hip_runtime.h>
#include <stdint.h>

typedef __attribute__((ext_vector_type(8))) short short8;
typedef __attribute__((ext_vector_type(4))) float f32x4;
typedef __attribute__((ext_vector_type(16))) float f32x16;
typedef __attribute__((ext_vector_type(4))) unsigned u32x4;

#define DEVINL __device__ __forceinline__

DEVINL unsigned short f2bf(float f) {
  unsigned u = __float_as_uint(f);
  u = (u + 0x7FFFu + ((u >> 16) & 1u)) >> 16;
  return (unsigned short)u;
}

DEVINL float bf2f(unsigned short s) {
  return __uint_as_float(((unsigned)s) << 16);
}

DEVINL void gload_lds16(const void* g, void* lds) {
  __builtin_amdgcn_global_load_lds(
      (const __attribute__((address_space(1))) unsigned int*)g,
      (__attribute__((address_space(3))) unsigned int*)lds, 16, 0, 0);
}

DEVINL float fexp2(float x) {
  float r;
  asm("v_exp_f32 %0, %1" : "=v"(r) : "v"(x));
  return r;
}

DEVINL unsigned cvtpk(float lo, float hi) {
  unsigned r;
  asm("v_cvt_pk_bf16_f32 %0, %1, %2" : "=v"(r) : "v"(lo), "v"(hi));
  return r;
}

DEVINL void pl32swap(unsigned& a, unsigned& b) {
  asm("v_permlane32_swap_b32 %0, %1" : "+v"(a), "+v"(b));
}

// ---------------- conversion kernels ----------------

__global__ void cvt4(const float* __restrict__ in, unsigned short* __restrict__ out,
                     float scale, int n4) {
  int i = blockIdx.x * blockDim.x + threadIdx.x;
  if (i >= n4) return;
  float4 v = ((const float4*)in)[i];
  ushort4 o;
  o.x = f2bf(v.x * scale); o.y = f2bf(v.y * scale);
  o.z = f2bf(v.z * scale); o.w = f2bf(v.w * scale);
  ((ushort4*)out)[i] = o;
}

// out[Nd][Kd] = in[Kd][Nd]  (bf16 convert)
__global__ void transpose_cvt(const float* __restrict__ in, unsigned short* __restrict__ out,
                              int Kd, int Nd) {
  int k = blockIdx.x * 32 + (threadIdx.x & 31);
  int n = blockIdx.y * 8 + (threadIdx.x >> 5);
  if (k < Kd && n < Nd) out[(size_t)n * Kd + k] = f2bf(in[(size_t)k * Nd + n]);
}

// WoT[d][h*64+e] = Wo[h][d][e] ; Wo is [8][512][64]
__global__ void wo_repack(const float* __restrict__ in, unsigned short* __restrict__ out) {
  int idx = blockIdx.x * 256 + threadIdx.x;
  if (idx >= 512 * 512) return;
  int d = idx >> 9, j = idx & 511, h = j >> 6, e = j & 63;
  out[idx] = f2bf(in[(size_t)h * 32768 + (size_t)d * 64 + e]);
}

// out[e] = sum_d b[d] * bf2f(W[e*512+d]) ; grid 512 blocks x 64 threads
__global__ void bias_fold(const float* __restrict__ b, const unsigned short* __restrict__ W,
                          float* __restrict__ out) {
  int e = blockIdx.x, l = threadIdx.x;
  short8 wv = *(const short8*)&W[(size_t)e * 512 + l * 8];
  float acc = 0.f;
#pragma unroll
  for (int j = 0; j < 8; ++j)
    acc += b[l * 8 + j] * bf2f((unsigned short)wv[j]);
#pragma unroll
  for (int off = 1; off < 64; off <<= 1) acc += __shfl_xor(acc, off, 64);
  if (l == 0) out[e] = acc;
}

// VT[((bh)*64 + e)*2048 + n] = VH[(b*2048+n)*512 + h*64 + e]
__global__ __launch_bounds__(256) void v_transpose(const unsigned short* __restrict__ VH,
                                                   unsigned short* __restrict__ VT) {
  const int bh = blockIdx.x, t = blockIdx.y;
  const int b = bh >> 3, h = bh & 7;
  __shared__ __align__(16) unsigned short L[128 * 72];
  const int tid = threadIdx.x;
#pragma unroll
  for (int i = 0; i < 4; ++i) {
    int c = i * 256 + tid, kk = c >> 3, cr = c & 7;
    *(short8*)&L[kk * 72 + cr * 8] =
        *(const short8*)&VH[(size_t)(b * 2048 + t * 128 + kk) * 512 + h * 64 + cr * 8];
  }
  __syncthreads();
#pragma unroll
  for (int i = 0; i < 4; ++i) {
    int c = i * 256 + tid, e = c >> 4, ckn = c & 15;
    short8 v;
#pragma unroll
    for (int j = 0; j < 8; ++j) v[j] = L[(ckn * 8 + j) * 72 + e];
    *(short8*)&VT[((size_t)bh * 64 + e) * 2048 + t * 128 + ckn * 8] = v;
  }
}

// ---------------- GEMM: C[M,N] = A[M,K] * Bt[N,K]^T (+bias)(+relu) ----------------
template <int EPI, typename TOut>
__global__ __launch_bounds__(256) void gemm_bt(
    const unsigned short* __restrict__ A, const unsigned short* __restrict__ Bt,
    const float* __restrict__ bias, TOut* __restrict__ C, int M, int N, int K) {
  __shared__ __align__(16) unsigned short As[128 * 32];
  __shared__ __align__(16) unsigned short Bs[128 * 32];
  const int m0 = blockIdx.x * 128, n0 = blockIdx.y * 128;
  const int tid = threadIdx.x, w = tid >> 6, l = tid & 63;
  const int wm = w >> 1, wn = w & 1;
  const int lr = l & 15, lg = l >> 4;

  f32x4 zero4 = {0.f, 0.f, 0.f, 0.f};
  f32x4 acc[4][4];
#pragma unroll
  for (int i = 0; i < 4; ++i)
#pragma unroll
    for (int j = 0; j < 4; ++j) acc[i][j] = zero4;

  for (int k0 = 0; k0 < K; k0 += 32) {
#pragma unroll
    for (int i = 0; i < 2; ++i) {
      const int cb = w * 64 + i * 256;
      const int c = cb + l;
      const int row = c >> 2, ce = (c & 3) * 8;
      gload_lds16(A + (size_t)(m0 + row) * K + k0 + ce, (char*)As + cb * 16);
      gload_lds16(Bt + (size_t)(n0 + row) * K + k0 + ce, (char*)Bs + cb * 16);
    }
    asm volatile("s_waitcnt vmcnt(0)" ::: "memory");
    __syncthreads();

    short8 af[4], bf[4];
#pragma unroll
    for (int mi = 0; mi < 4; ++mi)
      af[mi] = *(const short8*)&As[(wm * 64 + mi * 16 + lr) * 32 + lg * 8];
#pragma unroll
    for (int ni = 0; ni < 4; ++ni)
      bf[ni] = *(const short8*)&Bs[(wn * 64 + ni * 16 + lr) * 32 + lg * 8];
#pragma unroll
    for (int mi = 0; mi < 4; ++mi)
#pragma unroll
      for (int ni = 0; ni < 4; ++ni)
        acc[mi][ni] = __builtin_amdgcn_mfma_f32_16x16x32_bf16(af[mi], bf[ni], acc[mi][ni], 0, 0, 0);
    __syncthreads();
  }

#pragma unroll
  for (int ni = 0; ni < 4; ++ni) {
    const int col = n0 + wn * 64 + ni * 16 + lr;
    float bv = (EPI >= 1) ? bias[col] : 0.f;
#pragma unroll
    for (int mi = 0; mi < 4; ++mi) {
      const int row = m0 + wm * 64 + mi * 16 + lg * 4;
#pragma unroll
      for (int r = 0; r < 4; ++r) {
        float v = acc[mi][ni][r] + bv;
        if (EPI == 2) v = fmaxf(v, 0.f);
        if constexpr (sizeof(TOut) == 2)
          C[(size_t)(row + r) * N + col] = (TOut)f2bf(v);
        else
          C[(size_t)(row + r) * N + col] = v;
      }
    }
  }
}

// ---------------- flash attention, swapped-operand 32x32 ----------------
// Q,K: [B*2048, 512] bf16 head-sliced (S pre-scaled to log2 domain via Wq);
// VT: [bh][64 e][2048 n] bf16. grid (64 bh, 8 q-blocks), block 512 (8 waves x 32 q).
DEVINL void stage_kv(const unsigned short* Kp, const unsigned short* Vp,
                     char* klb, char* vtb, int tid, int k0) {
  const int row = tid >> 3, cs = tid & 7;
  const int sl = (cs ^ (row & 7)) * 8;
  gload_lds16(Kp + (size_t)(k0 + row) * 512 + sl, klb + tid * 16);
  gload_lds16(Vp + (size_t)row * 2048 + k0 + sl, vtb + tid * 16);
}

__global__ __launch_bounds__(512, 4) void attn_sw(
    const unsigned short* __restrict__ Q, const unsigned short* __restrict__ Kh,
    const unsigned short* __restrict__ VT, unsigned short* __restrict__ O) {
  const int bh = blockIdx.x, b = bh >> 3, h = bh & 7;
  const int q0 = blockIdx.y * 256;
  const int tid = threadIdx.x, w = tid >> 6, l = tid & 63;
  const int lq = l & 31, hi = l >> 5;
  const size_t baseBH = (size_t)b * 2048 * 512 + (size_t)h * 64;
  const size_t baseVT = (size_t)bh * 64 * 2048;

  __shared__ __align__(16) unsigned short Kl[2][64 * 64];
  __shared__ __align__(16) unsigned short Vt[2][64 * 64];
  __shared__ __align__(16) unsigned short eps[8][32][68];  // Q staging + epilogue

  const unsigned short* Kp = Kh + baseBH;
  const unsigned short* Vp = VT + baseVT;

  // ---- stage Q (coalesced, linear) + first K/V tile ----
  unsigned short* qs = &eps[0][0][0];
#pragma unroll
  for (int i = 0; i < 4; ++i) {
    int c = i * 512 + tid, row = c >> 3, cs = c & 7;
    gload_lds16(Q + baseBH + (size_t)(q0 + row) * 512 + cs * 8, (char*)qs + c * 16);
  }
  stage_kv(Kp, Vp, (char*)Kl[0], (char*)Vt[0], tid, 0);
  asm volatile("s_waitcnt vmcnt(0)" ::: "memory");
  __syncthreads();

  short8 qf[4];
#pragma unroll
  for (int kc = 0; kc < 4; ++kc)
    qf[kc] = *(const short8*)&qs[(w * 32 + lq) * 64 + kc * 16 + hi * 8];
  __syncthreads();  // everyone done reading qs before any reuse

  f32x16 ot0 = {0,0,0,0,0,0,0,0,0,0,0,0,0,0,0,0};
  f32x16 ot1 = {0,0,0,0,0,0,0,0,0,0,0,0,0,0,0,0};
  float m_run = -1e30f, l_run = 0.f;
  const int xs = (lq & 7);  // swizzle key for this lane's rows

  for (int t = 0; t < 32; ++t) {
    const int cur = t & 1;
    if (t + 1 < 32)
      stage_kv(Kp, Vp, (char*)Kl[cur ^ 1], (char*)Vt[cur ^ 1], tid, (t + 1) * 64);

    const char* klc = (const char*)Kl[cur];
    const char* vtc = (const char*)Vt[cur];

    // ---- S^T = K Q^T (32x32 tiles; col = q = lq) ----
    f32x16 st0 = {0,0,0,0,0,0,0,0,0,0,0,0,0,0,0,0};
    f32x16 st1 = {0,0,0,0,0,0,0,0,0,0,0,0,0,0,0,0};
#pragma unroll
    for (int kc = 0; kc < 4; ++kc) {
      const int sl = ((kc * 2 + hi) ^ xs) * 16;
      short8 kf0 = *(const short8*)(klc + lq * 128 + sl);
      short8 kf1 = *(const short8*)(klc + (32 + lq) * 128 + sl);
      st0 = __builtin_amdgcn_mfma_f32_32x32x16_bf16(kf0, qf[kc], st0, 0, 0, 0);
      st1 = __builtin_amdgcn_mfma_f32_32x32x16_bf16(kf1, qf[kc], st1, 0, 0, 0);
    }

    // ---- online softmax in log2 domain, per-lane q ----
    float t8[8];
#pragma unroll
    for (int r = 0; r < 8; ++r)
      t8[r] = fmaxf(fmaxf(st0[r], st0[r + 8]), fmaxf(st1[r], st1[r + 8]));
    float mt = fmaxf(fmaxf(fmaxf(t8[0], t8[1]), fmaxf(t8[2], t8[3])),
                     fmaxf(fmaxf(t8[4], t8[5]), fmaxf(t8[6], t8[7])));
    mt = fmaxf(mt, __shfl_xor(mt, 32, 64));

    const int need = __any(mt > m_run + 8.0f);
    if (need) {
      float mn = fmaxf(m_run, mt);
      float al = fexp2(m_run - mn);
      m_run = mn;
      l_run *= al;
#pragma unroll
      for (int r = 0; r < 16; ++r) { ot0[r] *= al; ot1[r] *= al; }
    }
#pragma unroll
    for (int r = 0; r < 16; ++r) {
      st0[r] = fexp2(st0[r] - m_run);
      st1[r] = fexp2(st1[r] - m_run);
    }
    float s8[8];
#pragma unroll
    for (int r = 0; r < 8; ++r)
      s8[r] = (st0[r] + st0[r + 8]) + (st1[r] + st1[r + 8]);
    float rs = ((s8[0] + s8[1]) + (s8[2] + s8[3])) + ((s8[4] + s8[5]) + (s8[6] + s8[7]));
    rs += __shfl_xor(rs, 32, 64);
    l_run += rs;

    // ---- O^T += V^T P^T  (P packed in-register via cvt_pk + permlane32_swap) ----
#pragma unroll
    for (int kc = 0; kc < 4; ++kc) {
      const int c = kc & 1;
      float p0, p1, p2, p3, p4, p5, p6, p7;
      if (kc < 2) {
        p0 = st0[8*c+0]; p1 = st0[8*c+1]; p2 = st0[8*c+2]; p3 = st0[8*c+3];
        p4 = st0[8*c+4]; p5 = st0[8*c+5]; p6 = st0[8*c+6]; p7 = st0[8*c+7];
      } else {
        p0 = st1[8*c+0]; p1 = st1[8*c+1]; p2 = st1[8*c+2]; p3 = st1[8*c+3];
        p4 = st1[8*c+4]; p5 = st1[8*c+5]; p6 = st1[8*c+6]; p7 = st1[8*c+7];
      }
      unsigned X0 = cvtpk(p0, p1), X1 = cvtpk(p2, p3);
      unsigned Y0 = cvtpk(p4, p5), Y1 = cvtpk(p6, p7);
      pl32swap(X0, Y0);  // X0 -> w0, Y0 -> w2
      pl32swap(X1, Y1);  // X1 -> w1, Y1 -> w3
      u32x4 u = {X0, X1, Y0, Y1};
      short8 pfk = __builtin_bit_cast(short8, u);

      const int sl = ((kc * 2 + hi) ^ xs) * 16;
      short8 v0 = *(const short8*)(vtc + lq * 128 + sl);
      short8 v1 = *(const short8*)(vtc + (32 + lq) * 128 + sl);
      ot0 = __builtin_amdgcn_mfma_f32_32x32x16_bf16(v0, pfk, ot0, 0, 0, 0);
      ot1 = __builtin_amdgcn_mfma_f32_32x32x16_bf16(v1, pfk, ot1, 0, 0, 0);
    }

    asm volatile("s_waitcnt vmcnt(0)" ::: "memory");
    __syncthreads();
  }

  // ---- epilogue: O^T regs -> LDS transpose -> coalesced global ----
  const float rinv = 1.0f / l_run;
#pragma unroll
  for (int r = 0; r < 16; ++r) {
    const int e = (r & 3) + 8 * (r >> 2) + 4 * hi;
    eps[w][lq][e] = f2bf(ot0[r] * rinv);
    eps[w][lq][e + 32] = f2bf(ot1[r] * rinv);
  }
#pragma unroll
  for (int i = 0; i < 4; ++i) {
    const int qq = i * 8 + (l >> 3), e0 = (l & 7) * 8;
    short8 v = *(const short8*)&eps[w][qq][e0];
    *(short8*)(O + baseBH + (size_t)(q0 + w * 32 + qq) * 512 + e0) = v;
  }
}

// ---------------- host launch ----------------

extern "C" void kernel_launch(void* const* d_in, const int* in_sizes, int n_in,
                              void* d_out, int out_size, void* d_ws, size_t ws_size,
                              hipStream_t stream) {
  const float* x1 = (const float*)d_in[0];
  const float* x2 = (const float*)d_in[1];
  const float* r  = (const float*)d_in[2];
  const float* W1 = (const float*)d_in[3];
  const float* b1 = (const float*)d_in[4];
  const float* W2 = (const float*)d_in[5];
  const float* b2 = (const float*)d_in[6];
  const float* Wq = (const float*)d_in[7];
  const float* Wk = (const float*)d_in[8];
  const float* Wv = (const float*)d_in[9];
  const float* Wo = (const float*)d_in[10];

  char* ws = (char*)d_ws;
  size_t off = 0;
  auto alloc = [&](size_t bytes) {
    char* p = ws + off;
    off = (off + bytes + 255) & ~(size_t)255;
    return p;
  };
  unsigned short* W1T = (unsigned short*)alloc(512 * 128 * 2);
  unsigned short* W2B = (unsigned short*)alloc(512 * 512 * 2);
  unsigned short* WqB = (unsigned short*)alloc(512 * 512 * 2);
  unsigned short* WkB = (unsigned short*)alloc(512 * 512 * 2);
  unsigned short* WvB = (unsigned short*)alloc(512 * 512 * 2);
  unsigned short* WoT = (unsigned short*)alloc(512 * 512 * 2);
  unsigned short* Fq  = (unsigned short*)alloc(512 * 512 * 2);
  unsigned short* Fk  = (unsigned short*)alloc(512 * 512 * 2);
  float* bqf = (float*)alloc(512 * 4);
  float* bkf = (float*)alloc(512 * 4);
  unsigned short* Xb  = (unsigned short*)alloc((size_t)16384 * 128 * 2);
  unsigned short* Hb  = (unsigned short*)alloc((size_t)16384 * 512 * 2);
  unsigned short* Rb  = (unsigned short*)alloc((size_t)16384 * 512 * 2);  // reused as VT
  unsigned short* QHb = (unsigned short*)alloc((size_t)16384 * 512 * 2);  // reused as O
  unsigned short* KHb = (unsigned short*)alloc((size_t)16384 * 512 * 2);
  unsigned short* VHb = (unsigned short*)alloc((size_t)16384 * 512 * 2);
  unsigned short* VT  = Rb;
  unsigned short* Ob  = QHb;

  const dim3 gBig(128, 4);   // 16384/128 x 512/128
  const dim3 gW(4, 4);       // 512/128 x 512/128

  // ---- weight prep ----
  transpose_cvt<<<dim3(4, 64), 256, 0, stream>>>(W1, W1T, 128, 512);
  cvt4<<<256, 256, 0, stream>>>(W2, W2B, 1.0f, 65536);
  // fold 1/sqrt(hd) AND log2(e) into Wq -> S comes out in log2 domain
  cvt4<<<256, 256, 0, stream>>>(Wq, WqB, 0.18033688f, 65536);
  cvt4<<<256, 256, 0, stream>>>(Wk, WkB, 1.0f, 65536);
  cvt4<<<256, 256, 0, stream>>>(Wv, WvB, 1.0f, 65536);
  wo_repack<<<1024, 256, 0, stream>>>(Wo, WoT);
  // fold W2 into head projections: Fq[e'][c] = sum_d WqB[e'][d] * W2[c][d]
  gemm_bt<0, unsigned short><<<gW, 256, 0, stream>>>(WqB, W2B, nullptr, Fq, 512, 512, 512);
  gemm_bt<0, unsigned short><<<gW, 256, 0, stream>>>(WkB, W2B, nullptr, Fk, 512, 512, 512);
  bias_fold<<<512, 64, 0, stream>>>(b2, WqB, bqf);
  bias_fold<<<512, 64, 0, stream>>>(b2, WkB, bkf);

  // ---- k path ----
  cvt4<<<2048, 256, 0, stream>>>(x1, Xb, 1.0f, 524288);
  gemm_bt<2, unsigned short><<<gBig, 256, 0, stream>>>(Xb, W1T, b1, Hb, 16384, 512, 128);
  gemm_bt<1, unsigned short><<<gBig, 256, 0, stream>>>(Hb, Fk, bkf, KHb, 16384, 512, 512);
  // ---- q path ----
  cvt4<<<2048, 256, 0, stream>>>(x2, Xb, 1.0f, 524288);
  gemm_bt<2, unsigned short><<<gBig, 256, 0, stream>>>(Xb, W1T, b1, Hb, 16384, 512, 128);
  gemm_bt<1, unsigned short><<<gBig, 256, 0, stream>>>(Hb, Fq, bqf, QHb, 16384, 512, 512);
  // ---- v path ----
  cvt4<<<8192, 256, 0, stream>>>(r, Rb, 1.0f, 2097152);
  gemm_bt<0, unsigned short><<<gBig, 256, 0, stream>>>(Rb, WvB, nullptr, VHb, 16384, 512, 512);
  v_transpose<<<dim3(64, 16), 256, 0, stream>>>(VHb, VT);
  // ---- attention (O aliases QHb: each block writes exactly the rows it read) ----
  attn_sw<<<dim3(64, 8), 512, 0, stream>>>(QHb, KHb, VT, Ob);
  // ---- output projection -> f32 ----
  gemm_bt<0, float><<<gBig, 256, 0, stream>>>(Ob, WoT, nullptr, (float*)d_out, 16384, 512, 512);
}

// Round 4
// 200.349 us; speedup vs baseline: 2.4680x; 1.2493x over previous
//
#include <hip/hip_runtime.h>
#include <stdint.h>

typedef __attribute__((ext_vector_type(8))) short short8;
typedef __attribute__((ext_vector_type(4))) float f32x4;
typedef __attribute__((ext_vector_type(16))) float f32x16;
typedef __attribute__((ext_vector_type(4))) unsigned u32x4;

#define DEVINL __device__ __forceinline__

DEVINL unsigned short f2bf(float f) {
  unsigned u = __float_as_uint(f);
  u = (u + 0x7FFFu + ((u >> 16) & 1u)) >> 16;
  return (unsigned short)u;
}

DEVINL void gload_lds16(const void* g, void* lds) {
  __builtin_amdgcn_global_load_lds(
      (const __attribute__((address_space(1))) unsigned int*)g,
      (__attribute__((address_space(3))) unsigned int*)lds, 16, 0, 0);
}

DEVINL float fexp2(float x) {
  float r;
  asm("v_exp_f32 %0, %1" : "=v"(r) : "v"(x));
  return r;
}

DEVINL unsigned cvtpk(float lo, float hi) {
  unsigned r;
  asm("v_cvt_pk_bf16_f32 %0, %1, %2" : "=v"(r) : "v"(lo), "v"(hi));
  return r;
}

DEVINL void pl32swap(unsigned& a, unsigned& b) {
  asm("v_permlane32_swap_b32 %0, %1" : "+v"(a), "+v"(b));
}

// ---------------- fused conversion kernels ----------------

// W2B/WqB/WkB/WvB bf16 conversion in one launch. grid 1024 x 256.
__global__ void cvt_wquad(const float* __restrict__ W2, const float* __restrict__ Wq,
                          const float* __restrict__ Wk, const float* __restrict__ Wv,
                          unsigned short* __restrict__ W2B, unsigned short* __restrict__ WqB,
                          unsigned short* __restrict__ WkB, unsigned short* __restrict__ WvB) {
  const int a = blockIdx.x >> 8;
  const int i = (blockIdx.x & 255) * 256 + threadIdx.x;
  const float* src = (a == 0) ? W2 : (a == 1) ? Wq : (a == 2) ? Wk : Wv;
  unsigned short* dst = (a == 0) ? W2B : (a == 1) ? WqB : (a == 2) ? WkB : WvB;
  const float scale = (a == 1) ? 0.18033688f : 1.0f;  // Wq: 1/sqrt(64) * log2(e)
  float4 v = ((const float4*)src)[i];
  ushort4 o;
  o.x = f2bf(v.x * scale); o.y = f2bf(v.y * scale);
  o.z = f2bf(v.z * scale); o.w = f2bf(v.w * scale);
  ((ushort4*)dst)[i] = o;
}

// W1T transpose + WoT repack + bias folds. grid 1536 x 256.
__global__ void prep_misc(const float* __restrict__ W1, const float* __restrict__ Wo,
                          const float* __restrict__ b2, const float* __restrict__ Wq,
                          const float* __restrict__ Wk,
                          unsigned short* __restrict__ W1T, unsigned short* __restrict__ WoT,
                          float* __restrict__ bqf, float* __restrict__ bkf) {
  const int bid = blockIdx.x, tid = threadIdx.x;
  if (bid < 256) {                       // W1T[n][k] = W1[k][n], 512x128
    int idx = bid * 256 + tid;
    int n = idx >> 7, k = idx & 127;
    W1T[idx] = f2bf(W1[(size_t)k * 512 + n]);
  } else if (bid < 1280) {               // WoT[d][h*64+e] = Wo[h][d][e]
    int idx = (bid - 256) * 256 + tid;
    int d = idx >> 9, j = idx & 511, h = j >> 6, e = j & 63;
    WoT[idx] = f2bf(Wo[(size_t)h * 32768 + (size_t)d * 64 + e]);
  } else {                               // bias folds from f32 weights
    int rid = (bid - 1280) * 4 + (tid >> 6);
    int l = tid & 63;
    int e = rid & 511, which = rid >> 9;
    const float* W = which ? Wk : Wq;
    float scale = which ? 1.0f : 0.18033688f;
    float acc = 0.f;
#pragma unroll
    for (int j = 0; j < 8; ++j)
      acc += b2[l * 8 + j] * W[(size_t)e * 512 + l * 8 + j];
    acc *= scale;
#pragma unroll
    for (int off = 1; off < 64; off <<= 1) acc += __shfl_xor(acc, off, 64);
    if (l == 0) (which ? bkf : bqf)[e] = acc;
  }
}

// x1,x2 -> Xb[32768][128]; r -> Rb. grid 12288 x 256.
__global__ void cvt_all(const float* __restrict__ x1, const float* __restrict__ x2,
                        const float* __restrict__ r,
                        unsigned short* __restrict__ Xb, unsigned short* __restrict__ Rb) {
  const int bid = blockIdx.x, tid = threadIdx.x;
  const float* src;
  unsigned short* dst;
  int i;
  if (bid < 2048)      { src = x1; dst = Xb;           i = bid * 256 + tid; }
  else if (bid < 4096) { src = x2; dst = Xb + 2097152; i = (bid - 2048) * 256 + tid; }
  else                 { src = r;  dst = Rb;           i = (bid - 4096) * 256 + tid; }
  float4 v = ((const float4*)src)[i];
  ushort4 o;
  o.x = f2bf(v.x); o.y = f2bf(v.y); o.z = f2bf(v.z); o.w = f2bf(v.w);
  ((ushort4*)dst)[i] = o;
}

// VT[((bh)*64 + e)*2048 + n] = VH[(b*2048+n)*512 + h*64 + e]
__global__ __launch_bounds__(256) void v_transpose(const unsigned short* __restrict__ VH,
                                                   unsigned short* __restrict__ VT) {
  const int bh = blockIdx.x, t = blockIdx.y;
  const int b = bh >> 3, h = bh & 7;
  __shared__ __align__(16) unsigned short L[128 * 72];
  const int tid = threadIdx.x;
#pragma unroll
  for (int i = 0; i < 4; ++i) {
    int c = i * 256 + tid, kk = c >> 3, cr = c & 7;
    *(short8*)&L[kk * 72 + cr * 8] =
        *(const short8*)&VH[(size_t)(b * 2048 + t * 128 + kk) * 512 + h * 64 + cr * 8];
  }
  __syncthreads();
#pragma unroll
  for (int i = 0; i < 4; ++i) {
    int c = i * 256 + tid, e = c >> 4, ckn = c & 15;
    short8 v;
#pragma unroll
    for (int j = 0; j < 8; ++j) v[j] = L[(ckn * 8 + j) * 72 + e];
    *(short8*)&VT[((size_t)bh * 64 + e) * 2048 + t * 128 + ckn * 8] = v;
  }
}

// ---------------- GEMM: C[M,N] = A[M,K]*Bt[N,K]^T, BK=64, swizzled LDS ----------------
// z-batched (up to 3 problems, same M/N/K). bias==null -> no bias. RELU template.
template <bool RELU, typename TOut>
__global__ __launch_bounds__(256) void gemm64(
    const unsigned short* A0, const unsigned short* B0, const float* bias0, TOut* C0,
    const unsigned short* A1, const unsigned short* B1, const float* bias1, TOut* C1,
    const unsigned short* A2, const unsigned short* B2, const float* bias2, TOut* C2,
    int M, int N, int K) {
  __shared__ __align__(16) char smem[32768];
  unsigned short* As = (unsigned short*)smem;
  unsigned short* Bs = (unsigned short*)(smem + 16384);

  const int z = blockIdx.z;
  const unsigned short* A = (z == 0) ? A0 : (z == 1) ? A1 : A2;
  const unsigned short* Bt = (z == 0) ? B0 : (z == 1) ? B1 : B2;
  const float* bias = (z == 0) ? bias0 : (z == 1) ? bias1 : bias2;
  TOut* C = (z == 0) ? C0 : (z == 1) ? C1 : C2;

  // XCD-chunked block swizzle; grid is (ncols, nrows)
  const int nx = gridDim.x;
  int id = blockIdx.y * nx + blockIdx.x;
  const int nwg = nx * gridDim.y;
  if ((nwg & 7) == 0) id = (id & 7) * (nwg >> 3) + (id >> 3);
  const int n0 = (id % nx) * 128, m0 = (id / nx) * 128;

  const int tid = threadIdx.x, w = tid >> 6, l = tid & 63;
  const int wm = w >> 1, wn = w & 1;
  const int lr = l & 15, lg = l >> 4;

  f32x4 zero4 = {0.f, 0.f, 0.f, 0.f};
  f32x4 acc[4][4];
#pragma unroll
  for (int i = 0; i < 4; ++i)
#pragma unroll
    for (int j = 0; j < 4; ++j) acc[i][j] = zero4;

  for (int k0 = 0; k0 < K; k0 += 64) {
#pragma unroll
    for (int i = 0; i < 4; ++i) {
      const int c = i * 256 + tid;                 // 16B chunk id, 0..1023
      const int row = c >> 3, ch = c & 7;
      const int sl = (ch ^ (row & 7)) * 8;         // pre-swizzled global source
      gload_lds16(A + (size_t)(m0 + row) * K + k0 + sl, (char*)As + c * 16);
      gload_lds16(Bt + (size_t)(n0 + row) * K + k0 + sl, (char*)Bs + c * 16);
    }
    asm volatile("s_waitcnt vmcnt(0)" ::: "memory");
    __syncthreads();

#pragma unroll
    for (int kk = 0; kk < 2; ++kk) {
      short8 af[4], bfr[4];
#pragma unroll
      for (int mi = 0; mi < 4; ++mi) {
        const int row = wm * 64 + mi * 16 + lr;
        af[mi] = *(const short8*)((const char*)As + row * 128 + (((kk * 4 + lg) ^ (row & 7)) * 16));
      }
#pragma unroll
      for (int ni = 0; ni < 4; ++ni) {
        const int row = wn * 64 + ni * 16 + lr;
        bfr[ni] = *(const short8*)((const char*)Bs + row * 128 + (((kk * 4 + lg) ^ (row & 7)) * 16));
      }
#pragma unroll
      for (int mi = 0; mi < 4; ++mi)
#pragma unroll
        for (int ni = 0; ni < 4; ++ni)
          acc[mi][ni] = __builtin_amdgcn_mfma_f32_16x16x32_bf16(af[mi], bfr[ni], acc[mi][ni], 0, 0, 0);
    }
    __syncthreads();
  }

#pragma unroll
  for (int ni = 0; ni < 4; ++ni) {
    const int col = n0 + wn * 64 + ni * 16 + lr;
    const float bv = bias ? bias[col] : 0.f;
#pragma unroll
    for (int mi = 0; mi < 4; ++mi) {
      const int row = m0 + wm * 64 + mi * 16 + lg * 4;
#pragma unroll
      for (int r = 0; r < 4; ++r) {
        float v = acc[mi][ni][r] + bv;
        if (RELU) v = fmaxf(v, 0.f);
        if constexpr (sizeof(TOut) == 2)
          C[(size_t)(row + r) * N + col] = (TOut)f2bf(v);
        else
          C[(size_t)(row + r) * N + col] = v;
      }
    }
  }
}

// ---------------- flash attention: ring-3 counted-vmcnt, swapped 32x32 ----------------
DEVINL void stage_kv(const unsigned short* Kp, const unsigned short* Vp,
                     char* kb, char* vb, int tid, int k0) {
  const int row = tid >> 3, cs = tid & 7;
  const int sl = (cs ^ (row & 7)) * 8;
  gload_lds16(Kp + (size_t)(k0 + row) * 512 + sl, kb + tid * 16);
  gload_lds16(Vp + (size_t)row * 2048 + k0 + sl, vb + tid * 16);
}

__global__ __launch_bounds__(512) void attn_sw(
    const unsigned short* __restrict__ Q, const unsigned short* __restrict__ Kh,
    const unsigned short* __restrict__ VT, unsigned short* __restrict__ O) {
  const int bh = blockIdx.x, b = bh >> 3, h = bh & 7;
  const int q0 = blockIdx.y * 256;
  const int tid = threadIdx.x, w = tid >> 6, l = tid & 63;
  const int lq = l & 31, hi = l >> 5;
  const size_t baseBH = (size_t)b * 2048 * 512 + (size_t)h * 64;

  __shared__ __align__(16) char smem[49152];  // K ring 3x8K | V ring 3x8K; eps overlays
  char* vb0 = smem + 24576;

  const unsigned short* Kp = Kh + baseBH;
  const unsigned short* Vp = VT + (size_t)bh * 64 * 2048;

  // ---- Q direct to registers (L2-hot, once per block) ----
  short8 qf[4];
  {
    const unsigned short* qp = Q + baseBH + (size_t)(q0 + w * 32 + lq) * 512 + hi * 8;
#pragma unroll
    for (int kc = 0; kc < 4; ++kc) qf[kc] = *(const short8*)(qp + kc * 16);
  }

  f32x16 ot0 = {0,0,0,0,0,0,0,0,0,0,0,0,0,0,0,0};
  f32x16 ot1 = {0,0,0,0,0,0,0,0,0,0,0,0,0,0,0,0};
  float m_run = -1e30f, l_run = 0.f;
  const int xs = (lq & 7);

  stage_kv(Kp, Vp, smem, vb0, tid, 0);
  stage_kv(Kp, Vp, smem + 8192, vb0 + 8192, tid, 64);

  for (int t = 0; t < 32; ++t) {
    if (t < 31) asm volatile("s_waitcnt vmcnt(2)" ::: "memory");
    else        asm volatile("s_waitcnt vmcnt(0)" ::: "memory");
    __syncthreads();
    if (t < 30) {
      const int tn = t + 2, rb = tn - (tn / 3) * 3;
      stage_kv(Kp, Vp, smem + rb * 8192, vb0 + rb * 8192, tid, tn * 64);
    }
    const int cb = t - (t / 3) * 3;
    const char* klc = smem + cb * 8192;
    const char* vtc = vb0 + cb * 8192;

    // ---- S^T = K Q^T ----
    f32x16 st0 = {0,0,0,0,0,0,0,0,0,0,0,0,0,0,0,0};
    f32x16 st1 = {0,0,0,0,0,0,0,0,0,0,0,0,0,0,0,0};
    __builtin_amdgcn_s_setprio(1);
#pragma unroll
    for (int kc = 0; kc < 4; ++kc) {
      const int sl = ((kc * 2 + hi) ^ xs) * 16;
      short8 kf0 = *(const short8*)(klc + lq * 128 + sl);
      short8 kf1 = *(const short8*)(klc + (32 + lq) * 128 + sl);
      st0 = __builtin_amdgcn_mfma_f32_32x32x16_bf16(kf0, qf[kc], st0, 0, 0, 0);
      st1 = __builtin_amdgcn_mfma_f32_32x32x16_bf16(kf1, qf[kc], st1, 0, 0, 0);
    }
    __builtin_amdgcn_s_setprio(0);

    // ---- online softmax (log2 domain), per-lane q ----
    float t8[8];
#pragma unroll
    for (int r = 0; r < 8; ++r)
      t8[r] = fmaxf(fmaxf(st0[r], st0[r + 8]), fmaxf(st1[r], st1[r + 8]));
    float mt = fmaxf(fmaxf(fmaxf(t8[0], t8[1]), fmaxf(t8[2], t8[3])),
                     fmaxf(fmaxf(t8[4], t8[5]), fmaxf(t8[6], t8[7])));
    mt = fmaxf(mt, __shfl_xor(mt, 32, 64));

    if (__any(mt > m_run + 8.0f)) {
      float mn = fmaxf(m_run, mt);
      float al = fexp2(m_run - mn);
      m_run = mn;
      l_run *= al;
#pragma unroll
      for (int r = 0; r < 16; ++r) { ot0[r] *= al; ot1[r] *= al; }
    }
#pragma unroll
    for (int r = 0; r < 16; ++r) {
      st0[r] = fexp2(st0[r] - m_run);
      st1[r] = fexp2(st1[r] - m_run);
    }
    float s8[8];
#pragma unroll
    for (int r = 0; r < 8; ++r)
      s8[r] = (st0[r] + st0[r + 8]) + (st1[r] + st1[r + 8]);
    float rs = ((s8[0] + s8[1]) + (s8[2] + s8[3])) + ((s8[4] + s8[5]) + (s8[6] + s8[7]));
    rs += __shfl_xor(rs, 32, 64);
    l_run += rs;

    // ---- O^T += V^T P^T ----
    __builtin_amdgcn_s_setprio(1);
#pragma unroll
    for (int kc = 0; kc < 4; ++kc) {
      const int c = kc & 1;
      float p0, p1, p2, p3, p4, p5, p6, p7;
      if (kc < 2) {
        p0 = st0[8*c+0]; p1 = st0[8*c+1]; p2 = st0[8*c+2]; p3 = st0[8*c+3];
        p4 = st0[8*c+4]; p5 = st0[8*c+5]; p6 = st0[8*c+6]; p7 = st0[8*c+7];
      } else {
        p0 = st1[8*c+0]; p1 = st1[8*c+1]; p2 = st1[8*c+2]; p3 = st1[8*c+3];
        p4 = st1[8*c+4]; p5 = st1[8*c+5]; p6 = st1[8*c+6]; p7 = st1[8*c+7];
      }
      unsigned X0 = cvtpk(p0, p1), X1 = cvtpk(p2, p3);
      unsigned Y0 = cvtpk(p4, p5), Y1 = cvtpk(p6, p7);
      pl32swap(X0, Y0);
      pl32swap(X1, Y1);
      u32x4 u = {X0, X1, Y0, Y1};
      short8 pfk = __builtin_bit_cast(short8, u);

      const int sl = ((kc * 2 + hi) ^ xs) * 16;
      short8 v0 = *(const short8*)(vtc + lq * 128 + sl);
      short8 v1 = *(const short8*)(vtc + (32 + lq) * 128 + sl);
      ot0 = __builtin_amdgcn_mfma_f32_32x32x16_bf16(v0, pfk, ot0, 0, 0, 0);
      ot1 = __builtin_amdgcn_mfma_f32_32x32x16_bf16(v1, pfk, ot1, 0, 0, 0);
    }
    __builtin_amdgcn_s_setprio(0);
  }

  __syncthreads();  // ring buffers dead; eps overlays smem

  // ---- epilogue: O^T regs -> LDS transpose -> coalesced global ----
  unsigned short (*eps)[32][66] = (unsigned short (*)[32][66])smem;
  const float rinv = 1.0f / l_run;
#pragma unroll
  for (int r = 0; r < 16; ++r) {
    const int e = (r & 3) + 8 * (r >> 2) + 4 * hi;
    eps[w][lq][e] = f2bf(ot0[r] * rinv);
    eps[w][lq][e + 32] = f2bf(ot1[r] * rinv);
  }
  asm volatile("s_waitcnt lgkmcnt(0)" ::: "memory");
  __builtin_amdgcn_sched_barrier(0);
#pragma unroll
  for (int i = 0; i < 4; ++i) {
    const int qq = i * 8 + (l >> 3), e0 = (l & 7) * 8;
    short8 v = *(const short8*)&eps[w][qq][e0];
    *(short8*)(O + baseBH + (size_t)(q0 + w * 32 + qq) * 512 + e0) = v;
  }
}

// ---------------- host launch ----------------

extern "C" void kernel_launch(void* const* d_in, const int* in_sizes, int n_in,
                              void* d_out, int out_size, void* d_ws, size_t ws_size,
                              hipStream_t stream) {
  const float* x1 = (const float*)d_in[0];
  const float* x2 = (const float*)d_in[1];
  const float* r  = (const float*)d_in[2];
  const float* W1 = (const float*)d_in[3];
  const float* b1 = (const float*)d_in[4];
  const float* W2 = (const float*)d_in[5];
  const float* b2 = (const float*)d_in[6];
  const float* Wq = (const float*)d_in[7];
  const float* Wk = (const float*)d_in[8];
  const float* Wv = (const float*)d_in[9];
  const float* Wo = (const float*)d_in[10];

  char* ws = (char*)d_ws;
  size_t off = 0;
  auto alloc = [&](size_t bytes) {
    char* p = ws + off;
    off = (off + bytes + 255) & ~(size_t)255;
    return p;
  };
  unsigned short* W1T = (unsigned short*)alloc(512 * 128 * 2);
  unsigned short* W2B = (unsigned short*)alloc(512 * 512 * 2);
  unsigned short* WqB = (unsigned short*)alloc(512 * 512 * 2);
  unsigned short* WkB = (unsigned short*)alloc(512 * 512 * 2);
  unsigned short* WvB = (unsigned short*)alloc(512 * 512 * 2);
  unsigned short* WoT = (unsigned short*)alloc(512 * 512 * 2);
  unsigned short* Fq  = (unsigned short*)alloc(512 * 512 * 2);
  unsigned short* Fk  = (unsigned short*)alloc(512 * 512 * 2);
  float* bqf = (float*)alloc(512 * 4);
  float* bkf = (float*)alloc(512 * 4);
  unsigned short* Xb  = (unsigned short*)alloc((size_t)32768 * 128 * 2);
  unsigned short* Hb  = (unsigned short*)alloc((size_t)32768 * 512 * 2);  // H1 | H2
  unsigned short* Rb  = (unsigned short*)alloc((size_t)16384 * 512 * 2);  // reused as VT
  unsigned short* QHb = (unsigned short*)alloc((size_t)16384 * 512 * 2);  // reused as O
  unsigned short* KHb = (unsigned short*)alloc((size_t)16384 * 512 * 2);
  unsigned short* VHb = (unsigned short*)alloc((size_t)16384 * 512 * 2);
  unsigned short* VT  = Rb;
  unsigned short* Ob  = QHb;

  // 1. weight cvts
  cvt_wquad<<<1024, 256, 0, stream>>>(W2, Wq, Wk, Wv, W2B, WqB, WkB, WvB);
  // 2. W1T + WoT + bias folds
  prep_misc<<<1536, 256, 0, stream>>>(W1, Wo, b2, Wq, Wk, W1T, WoT, bqf, bkf);
  // 3. fold W2 into head projections: F[e'][c] = sum_d W*B[e'][d] * W2[c][d]
  gemm64<false, unsigned short><<<dim3(4, 4, 2), 256, 0, stream>>>(
      WqB, W2B, nullptr, Fq,  WkB, W2B, nullptr, Fk,  WkB, W2B, nullptr, Fk,
      512, 512, 512);
  // 4. input cvts
  cvt_all<<<12288, 256, 0, stream>>>(x1, x2, r, Xb, Rb);
  // 5. L1 for both x1,x2: Hb = relu(Xb W1 + b1), M=32768
  gemm64<true, unsigned short><<<dim3(4, 256, 1), 256, 0, stream>>>(
      Xb, W1T, b1, Hb,  Xb, W1T, b1, Hb,  Xb, W1T, b1, Hb,
      32768, 512, 128);
  // 6. projections: KH = H1 Fk^T + bk ; QH = H2 Fq^T + bq ; VH = Rb Wv^T
  gemm64<false, unsigned short><<<dim3(4, 128, 3), 256, 0, stream>>>(
      Hb, Fk, bkf, KHb,
      Hb + (size_t)16384 * 512, Fq, bqf, QHb,
      Rb, WvB, nullptr, VHb,
      16384, 512, 512);
  // 7. V transpose (Rb consumed above; VT aliases it)
  v_transpose<<<dim3(64, 16), 256, 0, stream>>>(VHb, VT);
  // 8. attention (O aliases QHb: each block writes exactly the rows it read)
  attn_sw<<<dim3(64, 8), 512, 0, stream>>>(QHb, KHb, VT, Ob);
  // 9. output projection -> f32
  gemm64<false, float><<<dim3(4, 128, 1), 256, 0, stream>>>(
      Ob, WoT, nullptr, (float*)d_out,  Ob, WoT, nullptr, (float*)d_out,
      Ob, WoT, nullptr, (float*)d_out,
      16384, 512, 512);
}